// Round 1
// baseline (519.457 us; speedup 1.0000x reference)
//
#include <hip/hip_runtime.h>
#include <hip/hip_bf16.h>

// Fused 24-step LSTM forecaster, MI355X gfx950.
// 94208 independent cells; 64 cells/block, 16 cells/wave, bf16 MFMA 16x16x32.
// Wave-private LDS tiles -> no barriers in the time loop.

#define BN     512
#define HISTN  24
#define CNN    184
#define FN     17
#define PREDN  24
#define HIDN   32
#define INN    41
#define CELLS  (BN * CNN)          // 94208, divisible by 64 (1472 blocks)
#define FROW   (CNN * FN)          // 3128 floats per (b,t) feature row
#define PMROW  (HISTN * CNN)       // 4416 floats per b in pm25

typedef __attribute__((ext_vector_type(8))) short  short8;
typedef __attribute__((ext_vector_type(4))) float  float4v;

#define MFMA_B16(a, b, c) __builtin_amdgcn_mfma_f32_16x16x32_bf16(a, b, c, 0, 0, 0)

__device__ __forceinline__ short f2bf(float f) {
  union { float f; unsigned u; } v; v.f = f;
  unsigned r = v.u + 0x7fffu + ((v.u >> 16) & 1u);   // round-to-nearest-even
  return (short)(r >> 16);
}

__device__ __forceinline__ float fast_sigmoid(float x) {
  float e = __expf(-x);
  return __builtin_amdgcn_rcpf(1.0f + e);
}
__device__ __forceinline__ float fast_tanh(float x) {
  float e = __expf(2.0f * x);
  return 1.0f - 2.0f * __builtin_amdgcn_rcpf(1.0f + e);
}

// XOR swizzle on 8-element (16B) octets within a 64-elem row: breaks the
// 16-way bank conflict of the quarter-wave b128 A-frag read (m stride 128B).
__device__ __forceinline__ int swz(int m, int k) {
  return (((k >> 3) ^ (m & 7)) << 3) | (k & 7);
}
__device__ __forceinline__ short8 rdfrag(const short* rowp, int m, int octl) {
  return *(const short8*)(rowp + ((octl ^ (m & 7)) << 3));
}

__global__ __launch_bounds__(256, 2)
void lstm_fused(const float* __restrict__ pm25,
                const float* __restrict__ feat,
                const float* __restrict__ W_in,  const float* __restrict__ b_in,
                const float* __restrict__ W_ih,  const float* __restrict__ W_hh,
                const float* __restrict__ b_ih,  const float* __restrict__ b_hh,
                const float* __restrict__ W_out, const float* __restrict__ b_out,
                float* __restrict__ out)
{
  // Per-block LDS: 8KB + 8KB + 6KB = 22KB.
  __shared__ __align__(16) short Xs[64][64];   // [xn(24) | feat(17) | 0-pad], swizzled
  __shared__ __align__(16) short Zs[64][64];   // [xhid(32) | h(32)], swizzled
  __shared__ short buf[64][48];                // sliding window: [xn0(24) | preds(24)]

  const int tid   = threadIdx.x;
  const int w     = tid >> 6;        // wave 0..3
  const int lane  = tid & 63;
  const int q     = lane >> 4;       // 0..3
  const int c0    = lane & 15;
  const int mb    = w << 4;          // wave's first local row
  const int cell0 = blockIdx.x << 6;

  // ---------------- loop-invariant weight B-fragments (registers) -----------
  // B-frag (16x16x32): lane holds B[k = q*8+j][n = c0].
  short8 WzB[2][8];                  // [ks][nt]: k = ks*32+..., g = nt*16+c0
  #pragma unroll
  for (int ks = 0; ks < 2; ks++) {
    #pragma unroll
    for (int nt = 0; nt < 8; nt++) {
      short8 f;
      const int g = nt * 16 + c0;
      #pragma unroll
      for (int j = 0; j < 8; j++) {
        const int k = ks * 32 + q * 8 + j;
        const float v = (k < 32) ? W_ih[g * 32 + k] : W_hh[g * 32 + (k - 32)];
        f[j] = f2bf(v);
      }
      WzB[ks][nt] = f;
    }
  }
  short8 WxB[2][2];                  // W_in padded to K=64 (cols >=41 are zero)
  #pragma unroll
  for (int ks = 0; ks < 2; ks++) {
    #pragma unroll
    for (int nt = 0; nt < 2; nt++) {
      short8 f;
      const int j2 = nt * 16 + c0;
      #pragma unroll
      for (int j = 0; j < 8; j++) {
        const int k = ks * 32 + q * 8 + j;
        f[j] = (k < INN) ? f2bf(W_in[j2 * INN + k]) : (short)0;
      }
      WxB[ks][nt] = f;
    }
  }
  float bias_i[2], bias_f[2], bias_g[2], bias_o[2], binr[2], woutr[2];
  #pragma unroll
  for (int s = 0; s < 2; s++) {
    const int j = s * 16 + c0;
    bias_i[s] = b_ih[j]      + b_hh[j];
    bias_f[s] = b_ih[32 + j] + b_hh[32 + j];
    bias_g[s] = b_ih[64 + j] + b_hh[64 + j];
    bias_o[s] = b_ih[96 + j] + b_hh[96 + j];
    binr[s]   = b_in[j];
    woutr[s]  = W_out[j];
  }
  const float bo = b_out[0];

  // ---------------- per-thread staging role (wave-local cells only) ---------
  const int cl  = mb + (lane >> 2);            // local cell this thread stages
  const int sub = lane & 3;
  const int cg  = cell0 + cl;
  const int bb  = cg / CNN, cc = cg % CNN;
  const float* featBase = feat + ((size_t)(bb * 48 + HISTN)) * FROW + cc * FN;

  // init buf (xn0, bf16), zero-tail of Xs (k=41..63), h-region of Zs (k=32..63)
  {
    const float* src = pm25 + bb * PMROW + cc * HISTN;
    #pragma unroll
    for (int kk = 0; kk < 6; kk++) {
      const int k = sub * 6 + kk;
      buf[cl][k] = f2bf(src[k]);
    }
    for (int k = 41 + sub; k < 64; k += 4) Xs[cl][swz(cl, k)] = 0;
    for (int k = 32 + sub; k < 64; k += 4) Zs[cl][swz(cl, k)] = 0;
  }

  // output addressing for the 4 cells this lane's D-rows cover (only c0==0 writes)
  int outB[4], outC[4];
  #pragma unroll
  for (int r = 0; r < 4; r++) {
    const int cgr = cell0 + mb + q * 4 + r;
    outB[r] = cgr / CNN;
    outC[r] = cgr % CNN;
  }

  float cst[2][4];                   // cell state, C-layout resident in regs
  #pragma unroll
  for (int s = 0; s < 2; s++)
    #pragma unroll
    for (int r = 0; r < 4; r++) cst[s][r] = 0.f;

  // feature prefetch (software pipeline, one step ahead)
  float fv[5];
  #pragma unroll
  for (int i = 0; i < 5; i++) {
    const int f = sub * 5 + i;
    fv[i] = (f < FN) ? featBase[f] : 0.f;
  }

  #pragma unroll 1
  for (int t = 0; t < PREDN; t++) {
    // ---- stage X: xn window from buf, feat from prefetch regs ----
    #pragma unroll
    for (int kk = 0; kk < 6; kk++) {
      const int k = sub * 6 + kk;
      Xs[cl][swz(cl, k)] = buf[cl][t + k];
    }
    #pragma unroll
    for (int i = 0; i < 5; i++) {
      const int f = sub * 5 + i;
      if (f < FN) Xs[cl][swz(cl, 24 + f)] = f2bf(fv[i]);
    }
    if (t < PREDN - 1) {
      const float* p = featBase + (size_t)(t + 1) * FROW;
      #pragma unroll
      for (int i = 0; i < 5; i++) {
        const int f = sub * 5 + i;
        fv[i] = (f < FN) ? p[f] : 0.f;
      }
    }

    // ---- GEMM1: xhid = X @ W_in^T  (A-frag: lane row mb+c0, octet ks*4+q) ----
    const short* xrow = &Xs[mb + c0][0];
    const short8 xa = rdfrag(xrow, mb + c0, q);
    const short8 xb = rdfrag(xrow, mb + c0, 4 + q);
    float4v xh[2];
    #pragma unroll
    for (int nt = 0; nt < 2; nt++) {
      float4v a = {0.f, 0.f, 0.f, 0.f};
      a = MFMA_B16(xa, WxB[0][nt], a);
      a = MFMA_B16(xb, WxB[1][nt], a);
      xh[nt] = a;
    }
    // write xhid (+b_in) as bf16 into Z[:, 0:32]; D: row=mb+q*4+r, col=nt*16+c0
    #pragma unroll
    for (int s = 0; s < 2; s++) {
      const int j = s * 16 + c0;
      #pragma unroll
      for (int r = 0; r < 4; r++) {
        const int m = mb + q * 4 + r;
        Zs[m][swz(m, j)] = f2bf(xh[s][r] + binr[s]);
      }
    }

    // ---- GEMM2: gates = [xhid | h] @ [W_ih^T ; W_hh^T] ----
    const short* zrow = &Zs[mb + c0][0];
    const short8 za = rdfrag(zrow, mb + c0, q);
    const short8 zb = rdfrag(zrow, mb + c0, 4 + q);
    float4v acc[8];
    #pragma unroll
    for (int nt = 0; nt < 8; nt++) {
      float4v a = {0.f, 0.f, 0.f, 0.f};
      a = MFMA_B16(za, WzB[0][nt], a);
      a = MFMA_B16(zb, WzB[1][nt], a);
      acc[nt] = a;
    }

    // ---- epilogue: activations, state update, h -> Z, pred reduction ----
    float part[4] = {0.f, 0.f, 0.f, 0.f};
    #pragma unroll
    for (int s = 0; s < 2; s++) {
      const int j = s * 16 + c0;
      #pragma unroll
      for (int r = 0; r < 4; r++) {
        const float iv  = fast_sigmoid(acc[0 + s][r] + bias_i[s]);
        const float ff  = fast_sigmoid(acc[2 + s][r] + bias_f[s]);
        const float gv  = fast_tanh   (acc[4 + s][r] + bias_g[s]);
        const float ov  = fast_sigmoid(acc[6 + s][r] + bias_o[s]);
        const float cn  = ff * cst[s][r] + iv * gv;
        cst[s][r] = cn;
        const float hv = ov * fast_tanh(cn);
        const int m = mb + q * 4 + r;
        Zs[m][swz(m, 32 + j)] = f2bf(hv);
        part[r] += woutr[s] * hv;
      }
    }
    // reduce over the 16 lanes of this q-group (j = 0..31 coverage)
    #pragma unroll
    for (int r = 0; r < 4; r++) {
      float p = part[r];
      p += __shfl_xor(p, 1);
      p += __shfl_xor(p, 2);
      p += __shfl_xor(p, 4);
      p += __shfl_xor(p, 8);
      part[r] = p;
    }
    if (c0 == 0) {
      #pragma unroll
      for (int r = 0; r < 4; r++) {
        const float pr = part[r] + bo;
        out[(outB[r] * PREDN + t) * CNN + outC[r]] = pr;
        buf[mb + q * 4 + r][24 + t] = f2bf(pr);   // feeds xn window of later steps
      }
    }
  }
}

extern "C" void kernel_launch(void* const* d_in, const int* in_sizes, int n_in,
                              void* d_out, int out_size, void* d_ws, size_t ws_size,
                              hipStream_t stream) {
  (void)in_sizes; (void)n_in; (void)out_size; (void)d_ws; (void)ws_size;
  const float* pm25  = (const float*)d_in[0];
  const float* feat  = (const float*)d_in[1];
  // d_in[2] = time_feature, unused by the reference
  const float* W_in  = (const float*)d_in[3];
  const float* b_in  = (const float*)d_in[4];
  const float* W_ih  = (const float*)d_in[5];
  const float* W_hh  = (const float*)d_in[6];
  const float* b_ih  = (const float*)d_in[7];
  const float* b_hh  = (const float*)d_in[8];
  const float* W_out = (const float*)d_in[9];
  const float* b_out = (const float*)d_in[10];
  float* out = (float*)d_out;

  lstm_fused<<<dim3(CELLS / 64), dim3(256), 0, stream>>>(
      pm25, feat, W_in, b_in, W_ih, W_hh, b_ih, b_hh, W_out, b_out, out);
}